// Round 10
// baseline (324.665 us; speedup 1.0000x reference)
//
#include <hip/hip_runtime.h>
#include <stdint.h>

#define BDIM 4
#define CDIM 128
#define NDIM 4096
#define KSEL 10
#define NJOBS 2112  // 528 tile-pairs x 4 batches

typedef unsigned long long ull;
typedef __attribute__((ext_vector_type(8))) short short8;
typedef __attribute__((ext_vector_type(4))) float f32x4;

// CK-style global->LDS direct copy (16 B/lane).
__device__ __forceinline__ void async_cp16(void* lds, const void* g) {
  auto* gp = (const __attribute__((address_space(1))) unsigned int*)(uintptr_t)g;
  auto* lp = (__attribute__((address_space(3))) unsigned int*)(unsigned int)(uintptr_t)lds;
  __builtin_amdgcn_global_load_lds(gp, lp, 16, 0, 0);
}

__device__ __forceinline__ ull umax64(ull a, ull b) { return a > b ? a : b; }
__device__ __forceinline__ ull umin64(ull a, ull b) { return a > b ? b : a; }

__device__ __forceinline__ void merge2(ull& a0, ull& a1, ull b0, ull b1) {
  ull c0 = umax64(a0, b0);
  ull c1 = umax64(umin64(a0, b0), umax64(a1, b1));
  a0 = c0; a1 = c1;
}

__device__ __forceinline__ ull makekey(float s, unsigned low) {
  unsigned u = __float_as_uint(s);
  unsigned mono = u ^ ((unsigned)(((int)u) >> 31) | 0x80000000u);
  return ((ull)mono << 32) | (ull)low;
}

// round-to-nearest-even f32 -> bf16 (as u16)
__device__ __forceinline__ unsigned short bf16rne(float f) {
  unsigned u = __float_as_uint(f);
  unsigned r = u + 0x7fffu + ((u >> 16) & 1u);
  return (unsigned short)(r >> 16);
}
__device__ __forceinline__ float bf16tof(unsigned short h) {
  return __uint_as_float(((unsigned)h) << 16);
}

// ---------------------------------------------------------------------------
// Kernel A: xx[b][n] = sum_c x[b][c][n]^2
// ---------------------------------------------------------------------------
__global__ __launch_bounds__(256) void xx_kernel(const float* __restrict__ x,
                                                 float* __restrict__ xx) {
  int t = threadIdx.x;
  int nl = t >> 2;
  int part = t & 3;
  int g = blockIdx.x * 64 + nl;
  int b = g >> 12;
  int n = g & (NDIM - 1);
  const float* xp = x + (size_t)b * CDIM * NDIM + n;
  float s = 0.f;
  int c0 = part * 32;
#pragma unroll
  for (int i = 0; i < 32; ++i) {
    float v = xp[(size_t)(c0 + i) * NDIM];
    s += v * v;
  }
  s += __shfl_xor(s, 1, 4);
  s += __shfl_xor(s, 2, 4);
  if (part == 0) xx[g] = s;
}

// ---------------------------------------------------------------------------
// Kernel W: hi/lo bf16 split of W (RNE). W[o][c] row-major -> Whi/Wlo same
// layout (MFMA A-side: 8 contiguous k=c per lane). Also inits job counter.
// ---------------------------------------------------------------------------
__global__ __launch_bounds__(256) void wsplit_kernel(const float* __restrict__ W,
                                                     unsigned short* __restrict__ Whi,
                                                     unsigned short* __restrict__ Wlo,
                                                     unsigned* __restrict__ ctr) {
  int o = blockIdx.x, c = threadIdx.x;
  if (o == 0 && c == 0) *ctr = 0u;
  float v = W[o * 256 + c];
  unsigned short h = bf16rne(v);
  unsigned short lo = bf16rne(v - bf16tof(h));
  Whi[o * 256 + c] = h;
  Wlo[o * 256 + c] = lo;
}

// ---------------------------------------------------------------------------
// Kernel T: xT[b][n][c] = x[b][c][n] (f32, exact). Needed as the MFMA B-side
// (n-major, c-contiguous) and by gatherT.
// ---------------------------------------------------------------------------
__global__ __launch_bounds__(256) void xtf_kernel(const float* __restrict__ x,
                                                  float* __restrict__ xt) {
  int bb = blockIdx.y;
  int n0 = blockIdx.x * 64;
  __shared__ float tile[128 * 65];  // +1 pad: conflict-free column reads
  const float* xb = x + (size_t)bb * CDIM * NDIM;
  int t = threadIdx.x;
#pragma unroll
  for (int it = 0; it < 32; ++it) {
    int e = t + 256 * it;
    int c = e >> 6, n = e & 63;
    tile[c * 65 + n] = xb[(size_t)c * NDIM + n0 + n];
  }
  __syncthreads();
  float* xo = xt + ((size_t)bb * NDIM + n0) * CDIM;
#pragma unroll
  for (int it = 0; it < 32; ++it) {
    int e = t + 256 * it;
    int n = e >> 7, c = e & 127;
    xo[(size_t)n * CDIM + c] = tile[c * 65 + n];
  }
}

// ---------------------------------------------------------------------------
// Kernel S: score GEMM -> per-(row, 64-col-group) top-2. R17 VERBATIM
// (151.2us measured; persistent blocks + atomic queue; scatter/tree epilogue;
// keys bit-identical to merge's rescan fmaf chain).
// ---------------------------------------------------------------------------
__global__ __launch_bounds__(256) void score_kernel(const float* __restrict__ x,
                                                    const float* __restrict__ xxg,
                                                    ull* __restrict__ pcall,
                                                    unsigned* __restrict__ ctr) {
  const int N = NDIM;
  int t = threadIdx.x;
  int tx = t & 15, ty = t >> 4;
  int tx4 = tx * 4, ty4 = ty * 4;

  __shared__ __align__(16) float smem[8192];
  __shared__ unsigned job_s;

  for (;;) {
    __syncthreads();
    if (t == 0) job_s = atomicAdd(ctr, 1u);
    __syncthreads();
    unsigned job = job_s;
    if (job >= NJOBS) break;

    int bb = job / 528;
    int p = job - bb * 528;
    int I = 0;
    while (p >= 32 - I) { p -= 32 - I; ++I; }
    int J = I + p;
    int n0 = I * 128, m0 = J * 128;

    ull* pcb = pcall + (size_t)bb * N * 128;
    const float* xb = x + (size_t)bb * CDIM * N;

    float acc[8][8];
#pragma unroll
    for (int i = 0; i < 8; ++i)
#pragma unroll
      for (int j = 0; j < 8; ++j) acc[i][j] = 0.f;

    auto stage = [&](float* buf, int ch) {
      int c0 = ch * 16;
#pragma unroll
      for (int pp = 0; pp < 2; ++pp) {
        int i4 = t + 256 * pp;
        async_cp16(&buf[i4 * 4], &xb[(size_t)(c0 + (i4 >> 5)) * N + n0 + (i4 & 31) * 4]);
      }
#pragma unroll
      for (int pp = 0; pp < 2; ++pp) {
        int i4 = t + 256 * pp;
        async_cp16(&buf[2048 + i4 * 4], &xb[(size_t)(c0 + (i4 >> 5)) * N + m0 + (i4 & 31) * 4]);
      }
    };

    stage(smem, 0);

    for (int ch = 0; ch < 8; ++ch) {
      __syncthreads();
      float* cur = smem + (ch & 1) * 4096;
      if (ch < 7) stage(smem + ((ch + 1) & 1) * 4096, ch + 1);

      float* xn_s = cur;
      float* xm_s = cur + 2048;
#pragma unroll 4
      for (int cc = 0; cc < 16; ++cc) {
        float4 a0 = *(const float4*)&xn_s[cc * 128 + ty4];
        float4 a1 = *(const float4*)&xn_s[cc * 128 + ty4 + 64];
        float4 b0 = *(const float4*)&xm_s[cc * 128 + tx4];
        float4 b1 = *(const float4*)&xm_s[cc * 128 + tx4 + 64];
        float av[8] = {a0.x, a0.y, a0.z, a0.w, a1.x, a1.y, a1.z, a1.w};
        float bv[8] = {b0.x, b0.y, b0.z, b0.w, b1.x, b1.y, b1.z, b1.w};
#pragma unroll
        for (int i = 0; i < 8; ++i)
#pragma unroll
          for (int j = 0; j < 8; ++j) acc[i][j] += av[i] * bv[j];
      }
    }

    const float* xxb = xxg + (size_t)bb * N;
    ulonglong2* lds2 = (ulonglong2*)smem;

    // ----- n-side -----
    {
      float4 w0 = *(const float4*)&xxb[m0 + tx4];
      float4 w1 = *(const float4*)&xxb[m0 + tx4 + 64];
      float xv[8] = {w0.x, w0.y, w0.z, w0.w, w1.x, w1.y, w1.z, w1.w};
      unsigned mlow[8];
#pragma unroll
      for (int j = 0; j < 8; ++j)
        mlow[j] = 4095u - (unsigned)(m0 + tx4 + (j & 3) + (j >> 2) * 64);

#pragma unroll
      for (int h = 0; h < 2; ++h) {
        __syncthreads();
#pragma unroll
        for (int ii = 0; ii < 4; ++ii) {
          int i = h * 4 + ii;
          ull k[8];
#pragma unroll
          for (int j = 0; j < 8; ++j)
            k[j] = makekey(__builtin_fmaf(2.f, acc[i][j], -xv[j]), mlow[j]);
          ull g0a = umax64(k[0], k[1]), g0b = umin64(k[0], k[1]);
          merge2(g0a, g0b, umax64(k[2], k[3]), umin64(k[2], k[3]));
          ull g1a = umax64(k[4], k[5]), g1b = umin64(k[4], k[5]);
          merge2(g1a, g1b, umax64(k[6], k[7]), umin64(k[6], k[7]));
          int r = ty4 + ii;
          int p0 = r * 2;
          int p1 = r * 2 + 1;
          ulonglong2 v0; v0.x = g0a; v0.y = g0b;
          ulonglong2 v1; v1.x = g1a; v1.y = g1b;
          lds2[p0 * 16 + (tx ^ (r & 15))] = v0;
          lds2[p1 * 16 + (tx ^ (r & 15))] = v1;
        }
        __syncthreads();
        if (t < 128) {
          int pair = t;
          int r = pair >> 1, g = pair & 1;
          int kx = (pair >> 1) & 15;
          ulonglong2 e0 = lds2[pair * 16 + (0 ^ kx)];
          ull c0 = e0.x, c1 = e0.y;
#pragma unroll
          for (int e = 1; e < 16; ++e) {
            ulonglong2 ev = lds2[pair * 16 + (e ^ kx)];
            merge2(c0, c1, ev.x, ev.y);
          }
          int row = n0 + h * 64 + r;
          ulonglong2 v; v.x = c0; v.y = c1;
          *(ulonglong2*)&pcb[(size_t)row * 128 + (2 * J + g) * 2] = v;
        }
      }
    }

    // ----- m-side -----
    if (J != I) {
      float4 u0 = *(const float4*)&xxb[n0 + ty4];
      float4 u1 = *(const float4*)&xxb[n0 + ty4 + 64];
      float uv[8] = {u0.x, u0.y, u0.z, u0.w, u1.x, u1.y, u1.z, u1.w};
      unsigned nlow[8];
#pragma unroll
      for (int i = 0; i < 8; ++i)
        nlow[i] = 4095u - (unsigned)(n0 + ty4 + (i & 3) + (i >> 2) * 64);

#pragma unroll
      for (int h = 0; h < 2; ++h) {
        __syncthreads();
#pragma unroll
        for (int jj = 0; jj < 4; ++jj) {
          int j = h * 4 + jj;
          ull k[8];
#pragma unroll
          for (int i = 0; i < 8; ++i)
            k[i] = makekey(__builtin_fmaf(2.f, acc[i][j], -uv[i]), nlow[i]);
          ull g0a = umax64(k[0], k[1]), g0b = umin64(k[0], k[1]);
          merge2(g0a, g0b, umax64(k[2], k[3]), umin64(k[2], k[3]));
          ull g1a = umax64(k[4], k[5]), g1b = umin64(k[4], k[5]);
          merge2(g1a, g1b, umax64(k[6], k[7]), umin64(k[6], k[7]));
          int cl = tx4 + jj;
          int p0 = cl * 2;
          int p1 = cl * 2 + 1;
          ulonglong2 v0; v0.x = g0a; v0.y = g0b;
          ulonglong2 v1; v1.x = g1a; v1.y = g1b;
          lds2[p0 * 16 + (ty ^ (cl & 15))] = v0;
          lds2[p1 * 16 + (ty ^ (cl & 15))] = v1;
        }
        __syncthreads();
        if (t < 128) {
          int pair = t;
          int cl = pair >> 1, ng = pair & 1;
          int kx = (pair >> 1) & 15;
          ulonglong2 e0 = lds2[pair * 16 + (0 ^ kx)];
          ull c0 = e0.x, c1 = e0.y;
#pragma unroll
          for (int e = 1; e < 16; ++e) {
            ulonglong2 ev = lds2[pair * 16 + (e ^ kx)];
            merge2(c0, c1, ev.x, ev.y);
          }
          int row = m0 + h * 64 + cl;
          ulonglong2 v; v.x = c0; v.y = c1;
          *(ulonglong2*)&pcb[(size_t)row * 128 + (2 * I + ng) * 2] = v;
        }
      }
    }
  }
}

// ---------------------------------------------------------------------------
// Kernel M: exact top-10 (R17 verbatim — strided x staging).
// ---------------------------------------------------------------------------
__global__ __launch_bounds__(256) void merge_kernel(const float* __restrict__ x,
                                                    const float* __restrict__ xxg,
                                                    const ull* __restrict__ pcall,
                                                    int* __restrict__ idxout) {
  int t = threadIdx.x;
  int lane = t & 63;
  int wv = t >> 6;
  int bb = blockIdx.y;
  int row = blockIdx.x * 4 + wv;
  const ull* pr = pcall + ((size_t)bb * NDIM + row) * 128;
  ulonglong2 c = ((const ulonglong2*)pr)[lane];
  ull c1 = c.x, c2 = c.y;
  unsigned orig0 = (unsigned)(c1 & 0xFFFFFFFFull);
  unsigned orig1 = (unsigned)(c2 & 0xFFFFFFFFull);

  const float* xb = x + (size_t)bb * CDIM * NDIM;
  const float* xxb = xxg + (size_t)bb * NDIM;

  __shared__ float xrow_s[4 * 128];
  xrow_s[wv * 128 + lane] = xb[(size_t)lane * NDIM + row];
  xrow_s[wv * 128 + 64 + lane] = xb[(size_t)(64 + lane) * NDIM + row];

  int my = 0;
  for (int s = 0; s < KSEL; ++s) {
    ull mx = c1;
#pragma unroll
    for (int off = 1; off < 64; off <<= 1) {
      ull o = __shfl_xor(mx, off);
      mx = o > mx ? o : mx;
    }
    if (lane == s) my = 4095 - (int)(unsigned)(mx & 0xFFFFFFFFull);
    if (s < KSEL - 1) {
      bool iswin = (c1 == mx);
      ull bal = __ballot(iswin && (c2 == 0ull));
      if (iswin) { c1 = c2; c2 = 0ull; }
      if (bal) {
        int g = (int)(__ffsll((long long)bal) - 1);
        unsigned e0 = __shfl(orig0, g), e1 = __shfl(orig1, g);
        int col = g * 64 + lane;
        const float* xc = xb + col;
        const float* xrs = xrow_s + wv * 128;
        float d = 0.f;
        for (int cc = 0; cc < 128; ++cc)
          d = __builtin_fmaf(xc[(size_t)cc * NDIM], xrs[cc], d);
        float sv = __builtin_fmaf(2.f, d, -xxb[col]);
        unsigned low = 4095u - (unsigned)col;
        ull key = makekey(sv, low);
        if (key >= mx || low == e0 || low == e1) key = 0ull;
        ull r1 = key;
#pragma unroll
        for (int off = 1; off < 64; off <<= 1) {
          ull o = __shfl_xor(r1, off);
          r1 = o > r1 ? o : r1;
        }
        ull key2 = (key == r1) ? 0ull : key;
        ull r2 = key2;
#pragma unroll
        for (int off = 1; off < 64; off <<= 1) {
          ull o = __shfl_xor(r2, off);
          r2 = o > r2 ? o : r2;
        }
        if (lane == g) { c1 = r1; c2 = r2; }
      }
    }
  }
  if (lane < KSEL)
    idxout[((size_t)bb * NDIM + row) * KSEL + lane] = my;
}

// ---------------------------------------------------------------------------
// Kernel C: MdT[b][n][c] = mean_k xT[b][idx[n][k]][c] - xT[b][n][c].
// Transposed output (MFMA B-side layout), written into the dead pc region.
// Same k-order scalar sum as before -> values bit-identical to old Md.
// Fully coalesced: wave per row, lanes span c.
// ---------------------------------------------------------------------------
__global__ __launch_bounds__(256) void gathert_kernel(const float* __restrict__ xt,
                                                      const int* __restrict__ idxg,
                                                      float* __restrict__ MdT) {
  int bb = blockIdx.y;
  int n0 = blockIdx.x * 128;
  int t = threadIdx.x;
  int w = t >> 6, l = t & 63;
  const float* xb = xt + (size_t)bb * NDIM * CDIM;
  const int* ib = idxg + (size_t)bb * NDIM * KSEL;
  float* mb = MdT + (size_t)bb * NDIM * CDIM;
  int c0 = l * 2;
  for (int i = 0; i < 32; ++i) {
    int n = n0 + w * 32 + i;
    const int* ip = ib + (size_t)n * KSEL;
    float sx = 0.f, sy = 0.f;
#pragma unroll
    for (int k = 0; k < KSEL; ++k) {
      float2 v = *(const float2*)&xb[(size_t)ip[k] * CDIM + c0];
      sx += v.x; sy += v.y;
    }
    float2 me = *(const float2*)&xb[(size_t)n * CDIM + c0];
    float2 r;
    r.x = sx * 0.1f - me.x;
    r.y = sy * 0.1f - me.y;
    *(float2*)&mb[(size_t)n * CDIM + c0] = r;
  }
}

// ---------------------------------------------------------------------------
// Kernel D (R18): out via MFMA, hi/lo bf16 split (3 products; lo*lo dropped,
// rel err ~2^-16 — pure-tolerance path, no selection impact).
// A = W[o][c] (Whi/Wlo, k-contiguous rows), B = srcT[n][c] (MdT/xT rows),
// D per m89: col=lane&15, row=(lane>>4)*4+reg. Block: 64o x 128n; 4 waves
// split n (32 each, 2 n-tiles) x 4 o-tiles. K=256 in 8 chunks of 32.
// B staged f32->bf16 hi/lo in LDS, row stride 40 u16 (80B, bank-balanced).
// ---------------------------------------------------------------------------
#define BSTRIDE 40  // u16 per LDS row (80 B)

__global__ __launch_bounds__(256) void out_kernel(const float* __restrict__ MdT,
                                                  const float* __restrict__ xT,
                                                  const unsigned short* __restrict__ Whi,
                                                  const unsigned short* __restrict__ Wlo,
                                                  const float* __restrict__ bias,
                                                  float* __restrict__ out) {
  const int N = NDIM;
  int bb = blockIdx.z;
  int o0 = blockIdx.y * 64;
  int n0 = blockIdx.x * 128;
  int t = threadIdx.x;
  int w = t >> 6, l = t & 63;

  __shared__ __align__(16) unsigned short blds[2 * 128 * BSTRIDE];  // hi | lo

  const float* MdTb = MdT + (size_t)bb * NDIM * CDIM;
  const float* xTb = xT + (size_t)bb * NDIM * CDIM;

  f32x4 acc[4][2];
#pragma unroll
  for (int i = 0; i < 4; ++i)
#pragma unroll
    for (int j = 0; j < 2; ++j) acc[i][j] = (f32x4){0.f, 0.f, 0.f, 0.f};

  // staging assignment: thread t -> local row n_l = t>>1, c-offset (t&1)*16
  int n_l = t >> 1;
  int ch16 = (t & 1) * 16;

  // preload chunk 0 source regs
  const float* r0 = MdTb + (size_t)(n0 + n_l) * CDIM + ch16;
  float4 s0 = *(const float4*)&r0[0];
  float4 s1 = *(const float4*)&r0[4];
  float4 s2 = *(const float4*)&r0[8];
  float4 s3 = *(const float4*)&r0[12];

#pragma unroll
  for (int ch = 0; ch < 8; ++ch) {
    __syncthreads();  // previous compute done reading LDS
    // convert + write chunk ch to LDS (hi plane, then lo plane)
    {
      float vv[16] = {s0.x, s0.y, s0.z, s0.w, s1.x, s1.y, s1.z, s1.w,
                      s2.x, s2.y, s2.z, s2.w, s3.x, s3.y, s3.z, s3.w};
      unsigned hw[8], lw[8];
#pragma unroll
      for (int e = 0; e < 8; ++e) {
        unsigned short h0 = bf16rne(vv[2 * e]);
        unsigned short h1 = bf16rne(vv[2 * e + 1]);
        unsigned short l0 = bf16rne(vv[2 * e] - bf16tof(h0));
        unsigned short l1 = bf16rne(vv[2 * e + 1] - bf16tof(h1));
        hw[e] = (unsigned)h0 | ((unsigned)h1 << 16);
        lw[e] = (unsigned)l0 | ((unsigned)l1 << 16);
      }
      char* base = (char*)blds + (size_t)n_l * (BSTRIDE * 2) + ch16 * 2;
      ((uint4*)base)[0] = make_uint4(hw[0], hw[1], hw[2], hw[3]);
      ((uint4*)(base + 16))[0] = make_uint4(hw[4], hw[5], hw[6], hw[7]);
      char* baseL = base + 128 * BSTRIDE * 2;
      ((uint4*)baseL)[0] = make_uint4(lw[0], lw[1], lw[2], lw[3]);
      ((uint4*)(baseL + 16))[0] = make_uint4(lw[4], lw[5], lw[6], lw[7]);
    }
    // issue loads for next chunk (clamped; redundant reload on last iter)
    {
      int chn = (ch < 7) ? ch + 1 : 7;
      const float* src = (chn < 4) ? MdTb : xTb;
      const float* rn = src + (size_t)(n0 + n_l) * CDIM + (chn & 3) * 32 + ch16;
      s0 = *(const float4*)&rn[0];
      s1 = *(const float4*)&rn[4];
      s2 = *(const float4*)&rn[8];
      s3 = *(const float4*)&rn[12];
    }
    __syncthreads();  // chunk ch LDS visible

    // fragments + MFMA
    int kcA = ch * 32;
    const char* bbase = (const char*)blds +
                        (size_t)(w * 32 + (l & 15)) * (BSTRIDE * 2) + (l >> 4) * 16;
    short8 bh0 = *(const short8*)bbase;
    short8 bh1 = *(const short8*)(bbase + 16 * (BSTRIDE * 2));
    short8 bl0 = *(const short8*)(bbase + 128 * BSTRIDE * 2);
    short8 bl1 = *(const short8*)(bbase + 128 * BSTRIDE * 2 + 16 * (BSTRIDE * 2));

    short8 ah[4], al[4];
#pragma unroll
    for (int ot = 0; ot < 4; ++ot) {
      size_t ai = (size_t)(o0 + ot * 16 + (l & 15)) * 256 + kcA + (l >> 4) * 8;
      ah[ot] = *(const short8*)&Whi[ai];
      al[ot] = *(const short8*)&Wlo[ai];
    }
#pragma unroll
    for (int ot = 0; ot < 4; ++ot) {
      acc[ot][0] = __builtin_amdgcn_mfma_f32_16x16x32_bf16(ah[ot], bh0, acc[ot][0], 0, 0, 0);
      acc[ot][0] = __builtin_amdgcn_mfma_f32_16x16x32_bf16(ah[ot], bl0, acc[ot][0], 0, 0, 0);
      acc[ot][0] = __builtin_amdgcn_mfma_f32_16x16x32_bf16(al[ot], bh0, acc[ot][0], 0, 0, 0);
      acc[ot][1] = __builtin_amdgcn_mfma_f32_16x16x32_bf16(ah[ot], bh1, acc[ot][1], 0, 0, 0);
      acc[ot][1] = __builtin_amdgcn_mfma_f32_16x16x32_bf16(ah[ot], bl1, acc[ot][1], 0, 0, 0);
      acc[ot][1] = __builtin_amdgcn_mfma_f32_16x16x32_bf16(al[ot], bh1, acc[ot][1], 0, 0, 0);
    }
  }

  // epilogue: D[row=(l>>4)*4+r][col=l&15] per tile; add bias, store
#pragma unroll
  for (int ot = 0; ot < 4; ++ot) {
    int obase = o0 + ot * 16 + (l >> 4) * 4;
    float4 bv = *(const float4*)&bias[obase];
#pragma unroll
    for (int j = 0; j < 2; ++j) {
      int ncol = n0 + w * 32 + j * 16 + (l & 15);
      float* po = out + ((size_t)(bb * 256 + obase)) * N + ncol;
      po[0] = acc[ot][j].x + bv.x;
      po[(size_t)N] = acc[ot][j].y + bv.y;
      po[(size_t)2 * N] = acc[ot][j].z + bv.z;
      po[(size_t)3 * N] = acc[ot][j].w + bv.w;
    }
  }
}

// ---------------------------------------------------------------------------
extern "C" void kernel_launch(void* const* d_in, const int* in_sizes, int n_in,
                              void* d_out, int out_size, void* d_ws, size_t ws_size,
                              hipStream_t stream) {
  const float* x = (const float*)d_in[0];     // (4,128,4096) fp32
  const float* W = (const float*)d_in[1];     // (256,256,1,1) fp32
  const float* bias = (const float*)d_in[2];  // (256,) fp32
  float* out = (float*)d_out;                 // (4,256,4096) fp32

  // ws carve: xx 64K | idx 640K | xT 8M (old Md slot) | pc 16M | Whi/Wlo 256K.
  // MdT overlays pc (dead after merge). Job counter lives in `out`.
  float* xx = (float*)d_ws;
  int* idx = (int*)((char*)d_ws + 65536);
  float* xT = (float*)((char*)d_ws + 65536 + 655360);
  const size_t fixed = 9109504;
  ull* pc = (ull*)((char*)d_ws + fixed);      // 16 MB candidates
  float* MdT = (float*)pc;                    // overlay: valid after merge
  size_t wt_off = (ws_size - 262144) & ~(size_t)255;
  unsigned short* Whi = (unsigned short*)((char*)d_ws + wt_off);
  unsigned short* Wlo = Whi + 256 * 256;
  unsigned* ctr = (unsigned*)out;

  xx_kernel<<<dim3(256), 256, 0, stream>>>(x, xx);
  wsplit_kernel<<<dim3(256), 256, 0, stream>>>(W, Whi, Wlo, ctr);
  xtf_kernel<<<dim3(64, 4), 256, 0, stream>>>(x, xT);
  score_kernel<<<dim3(768), 256, 0, stream>>>(x, xx, pc, ctr);
  merge_kernel<<<dim3(1024, 4), 256, 0, stream>>>(x, xx, pc, idx);
  gathert_kernel<<<dim3(32, 4), 256, 0, stream>>>(xT, idx, MdT);
  out_kernel<<<dim3(32, 4, 4), 256, 0, stream>>>(MdT, xT, Whi, Wlo, bias, out);
}

// Round 11
// 284.254 us; speedup vs baseline: 1.1422x; 1.1422x over previous
//
#include <hip/hip_runtime.h>
#include <stdint.h>

#define BDIM 4
#define CDIM 128
#define NDIM 4096
#define KSEL 10
#define NJOBS 2112  // 528 tile-pairs x 4 batches

typedef unsigned long long ull;

// CK-style global->LDS direct copy (16 B/lane).
__device__ __forceinline__ void async_cp16(void* lds, const void* g) {
  auto* gp = (const __attribute__((address_space(1))) unsigned int*)(uintptr_t)g;
  auto* lp = (__attribute__((address_space(3))) unsigned int*)(unsigned int)(uintptr_t)lds;
  __builtin_amdgcn_global_load_lds(gp, lp, 16, 0, 0);
}

__device__ __forceinline__ ull umax64(ull a, ull b) { return a > b ? a : b; }
__device__ __forceinline__ ull umin64(ull a, ull b) { return a > b ? b : a; }

// merge two sorted-desc pairs (a0>=a1),(b0>=b1) -> sorted top-2 of union
__device__ __forceinline__ void merge2(ull& a0, ull& a1, ull b0, ull b1) {
  ull c0 = umax64(a0, b0);
  ull c1 = umax64(umin64(a0, b0), umax64(a1, b1));
  a0 = c0; a1 = c1;
}

__device__ __forceinline__ ull makekey(float s, unsigned low) {
  unsigned u = __float_as_uint(s);
  unsigned mono = u ^ ((unsigned)(((int)u) >> 31) | 0x80000000u);
  return ((ull)mono << 32) | (ull)low;
}

// ---------------------------------------------------------------------------
// Kernel A: xx[b][n] = sum_c x[b][c][n]^2
// ---------------------------------------------------------------------------
__global__ __launch_bounds__(256) void xx_kernel(const float* __restrict__ x,
                                                 float* __restrict__ xx) {
  int t = threadIdx.x;
  int nl = t >> 2;
  int part = t & 3;
  int g = blockIdx.x * 64 + nl;
  int b = g >> 12;
  int n = g & (NDIM - 1);
  const float* xp = x + (size_t)b * CDIM * NDIM + n;
  float s = 0.f;
  int c0 = part * 32;
#pragma unroll
  for (int i = 0; i < 32; ++i) {
    float v = xp[(size_t)(c0 + i) * NDIM];
    s += v * v;
  }
  s += __shfl_xor(s, 1, 4);
  s += __shfl_xor(s, 2, 4);
  if (part == 0) xx[g] = s;
}

// ---------------------------------------------------------------------------
// Kernel W: WT[c][o] = W[o][c]. Also inits the persistent-score job counter
// (lives in `out`, which out_kernel fully overwrites later).
// ---------------------------------------------------------------------------
__global__ __launch_bounds__(256) void wtrans_kernel(const float* __restrict__ W,
                                                     float* __restrict__ WT,
                                                     unsigned* __restrict__ ctr) {
  if (blockIdx.x == 0 && threadIdx.x == 0) *ctr = 0u;
  int c = blockIdx.x, o = threadIdx.x;
  WT[c * 256 + o] = W[o * 256 + c];
}

// ---------------------------------------------------------------------------
// Kernel S: score GEMM (symmetry-halved) -> per-(row, 64-col-group) top-2.
// R17 config (measured 151.2us, VGPR 80): persistent blocks + atomic queue;
// plain av/bv inner loop (compiler schedules best — R16's source pipelining
// spilled acc to scratch); scatter/tree epilogue (R12). Keys bit-identical
// to merge's rescan fmaf chain.
// ---------------------------------------------------------------------------
__global__ __launch_bounds__(256) void score_kernel(const float* __restrict__ x,
                                                    const float* __restrict__ xxg,
                                                    ull* __restrict__ pcall,
                                                    unsigned* __restrict__ ctr) {
  const int N = NDIM;
  int t = threadIdx.x;
  int tx = t & 15, ty = t >> 4;
  int tx4 = tx * 4, ty4 = ty * 4;

  // 2 staging buffers x (xn[16][128] + xm[16][128]) = 8192 floats = 32 KB.
  // Reused as top-2 reduce scratch (exactly 32 KB) after each job's GEMM.
  __shared__ __align__(16) float smem[8192];
  __shared__ unsigned job_s;

  for (;;) {
    __syncthreads();  // prior job's scratch readers done; job_s safe to write
    if (t == 0) job_s = atomicAdd(ctr, 1u);
    __syncthreads();
    unsigned job = job_s;
    if (job >= NJOBS) break;

    int bb = job / 528;
    int p = job - bb * 528;
    int I = 0;
    while (p >= 32 - I) { p -= 32 - I; ++I; }
    int J = I + p;
    int n0 = I * 128, m0 = J * 128;

    ull* pcb = pcall + (size_t)bb * N * 128;
    const float* xb = x + (size_t)bb * CDIM * N;

    float acc[8][8];
#pragma unroll
    for (int i = 0; i < 8; ++i)
#pragma unroll
      for (int j = 0; j < 8; ++j) acc[i][j] = 0.f;

    // stage 16-channel chunk ch into buffer buf (xn at buf, xm at buf+2048)
    auto stage = [&](float* buf, int ch) {
      int c0 = ch * 16;
#pragma unroll
      for (int pp = 0; pp < 2; ++pp) {
        int i4 = t + 256 * pp;
        async_cp16(&buf[i4 * 4], &xb[(size_t)(c0 + (i4 >> 5)) * N + n0 + (i4 & 31) * 4]);
      }
#pragma unroll
      for (int pp = 0; pp < 2; ++pp) {
        int i4 = t + 256 * pp;
        async_cp16(&buf[2048 + i4 * 4], &xb[(size_t)(c0 + (i4 >> 5)) * N + m0 + (i4 & 31) * 4]);
      }
    };

    stage(smem, 0);  // prologue prefetch (chunk 0 -> buf 0)

    for (int ch = 0; ch < 8; ++ch) {
      __syncthreads();
      float* cur = smem + (ch & 1) * 4096;
      if (ch < 7) stage(smem + ((ch + 1) & 1) * 4096, ch + 1);

      float* xn_s = cur;
      float* xm_s = cur + 2048;
#pragma unroll 4
      for (int cc = 0; cc < 16; ++cc) {
        float4 a0 = *(const float4*)&xn_s[cc * 128 + ty4];
        float4 a1 = *(const float4*)&xn_s[cc * 128 + ty4 + 64];
        float4 b0 = *(const float4*)&xm_s[cc * 128 + tx4];
        float4 b1 = *(const float4*)&xm_s[cc * 128 + tx4 + 64];
        float av[8] = {a0.x, a0.y, a0.z, a0.w, a1.x, a1.y, a1.z, a1.w};
        float bv[8] = {b0.x, b0.y, b0.z, b0.w, b1.x, b1.y, b1.z, b1.w};
#pragma unroll
        for (int i = 0; i < 8; ++i)
#pragma unroll
          for (int j = 0; j < 8; ++j) acc[i][j] += av[i] * bv[j];
      }
    }

    const float* xxb = xxg + (size_t)bb * N;
    ulonglong2* lds2 = (ulonglong2*)smem;  // [pair 128][slot 16] ulonglong2

    // ----- n-side: rows n0.., groups 2J,2J+1 -----
    {
      float4 w0 = *(const float4*)&xxb[m0 + tx4];
      float4 w1 = *(const float4*)&xxb[m0 + tx4 + 64];
      float xv[8] = {w0.x, w0.y, w0.z, w0.w, w1.x, w1.y, w1.z, w1.w};
      unsigned mlow[8];
#pragma unroll
      for (int j = 0; j < 8; ++j)
        mlow[j] = 4095u - (unsigned)(m0 + tx4 + (j & 3) + (j >> 2) * 64);

#pragma unroll
      for (int h = 0; h < 2; ++h) {
        __syncthreads();  // prior smem users (GEMM / previous reduce) done
#pragma unroll
        for (int ii = 0; ii < 4; ++ii) {
          int i = h * 4 + ii;
          ull k[8];
#pragma unroll
          for (int j = 0; j < 8; ++j)
            k[j] = makekey(__builtin_fmaf(2.f, acc[i][j], -xv[j]), mlow[j]);
          ull g0a = umax64(k[0], k[1]), g0b = umin64(k[0], k[1]);
          merge2(g0a, g0b, umax64(k[2], k[3]), umin64(k[2], k[3]));
          ull g1a = umax64(k[4], k[5]), g1b = umin64(k[4], k[5]);
          merge2(g1a, g1b, umax64(k[6], k[7]), umin64(k[6], k[7]));
          int r = ty4 + ii;        // local row 0..63
          int p0 = r * 2;          // pair for group 2J
          int p1 = r * 2 + 1;      // pair for group 2J+1
          ulonglong2 v0; v0.x = g0a; v0.y = g0b;
          ulonglong2 v1; v1.x = g1a; v1.y = g1b;
          lds2[p0 * 16 + (tx ^ (r & 15))] = v0;
          lds2[p1 * 16 + (tx ^ (r & 15))] = v1;
        }
        __syncthreads();
        if (t < 128) {
          int pair = t;
          int r = pair >> 1, g = pair & 1;
          int kx = (pair >> 1) & 15;
          ulonglong2 e0 = lds2[pair * 16 + (0 ^ kx)];
          ull c0 = e0.x, c1 = e0.y;
#pragma unroll
          for (int e = 1; e < 16; ++e) {
            ulonglong2 ev = lds2[pair * 16 + (e ^ kx)];
            merge2(c0, c1, ev.x, ev.y);
          }
          int row = n0 + h * 64 + r;
          ulonglong2 v; v.x = c0; v.y = c1;
          *(ulonglong2*)&pcb[(size_t)row * 128 + (2 * J + g) * 2] = v;
        }
      }
    }

    // ----- m-side (off-diag): rows m0.., groups 2I,2I+1 -----
    if (J != I) {
      float4 u0 = *(const float4*)&xxb[n0 + ty4];
      float4 u1 = *(const float4*)&xxb[n0 + ty4 + 64];
      float uv[8] = {u0.x, u0.y, u0.z, u0.w, u1.x, u1.y, u1.z, u1.w};
      unsigned nlow[8];
#pragma unroll
      for (int i = 0; i < 8; ++i)
        nlow[i] = 4095u - (unsigned)(n0 + ty4 + (i & 3) + (i >> 2) * 64);

#pragma unroll
      for (int h = 0; h < 2; ++h) {
        __syncthreads();  // n-side (or previous half) reduce reads done
#pragma unroll
        for (int jj = 0; jj < 4; ++jj) {
          int j = h * 4 + jj;
          ull k[8];
#pragma unroll
          for (int i = 0; i < 8; ++i)
            k[i] = makekey(__builtin_fmaf(2.f, acc[i][j], -uv[i]), nlow[i]);
          ull g0a = umax64(k[0], k[1]), g0b = umin64(k[0], k[1]);
          merge2(g0a, g0b, umax64(k[2], k[3]), umin64(k[2], k[3]));
          ull g1a = umax64(k[4], k[5]), g1b = umin64(k[4], k[5]);
          merge2(g1a, g1b, umax64(k[6], k[7]), umin64(k[6], k[7]));
          int cl = tx4 + jj;       // local col 0..63
          int p0 = cl * 2;         // pair for group 2I
          int p1 = cl * 2 + 1;     // pair for group 2I+1
          ulonglong2 v0; v0.x = g0a; v0.y = g0b;
          ulonglong2 v1; v1.x = g1a; v1.y = g1b;
          lds2[p0 * 16 + (ty ^ (cl & 15))] = v0;
          lds2[p1 * 16 + (ty ^ (cl & 15))] = v1;
        }
        __syncthreads();
        if (t < 128) {
          int pair = t;
          int cl = pair >> 1, ng = pair & 1;
          int kx = (pair >> 1) & 15;
          ulonglong2 e0 = lds2[pair * 16 + (0 ^ kx)];
          ull c0 = e0.x, c1 = e0.y;
#pragma unroll
          for (int e = 1; e < 16; ++e) {
            ulonglong2 ev = lds2[pair * 16 + (e ^ kx)];
            merge2(c0, c1, ev.x, ev.y);
          }
          int row = m0 + h * 64 + cl;
          ulonglong2 v; v.x = c0; v.y = c1;
          *(ulonglong2*)&pcb[(size_t)row * 128 + (2 * I + ng) * 2] = v;
        }
      }
    }
  }
}

// ---------------------------------------------------------------------------
// Kernel M: exact top-10 from candidates. One wave per row; lane = group
// (64 cols each), holds the group's sorted top-2. 10 butterfly-argmax rounds;
// on lane exhaustion the wave recomputes that group's 64 scores from x
// (bitwise-identical fmaf chain), filters key<mx (+orig-idx exclusion),
// top-2 reduces, refills. Exact (hidden 3rd < stored 2nd <= extracted mx).
// Strided x staging (xT transpose was a measured net loss — R14, R18).
// ---------------------------------------------------------------------------
__global__ __launch_bounds__(256) void merge_kernel(const float* __restrict__ x,
                                                    const float* __restrict__ xxg,
                                                    const ull* __restrict__ pcall,
                                                    int* __restrict__ idxout) {
  int t = threadIdx.x;
  int lane = t & 63;
  int wv = t >> 6;
  int bb = blockIdx.y;
  int row = blockIdx.x * 4 + wv;
  const ull* pr = pcall + ((size_t)bb * NDIM + row) * 128;
  ulonglong2 c = ((const ulonglong2*)pr)[lane];
  ull c1 = c.x, c2 = c.y;
  unsigned orig0 = (unsigned)(c1 & 0xFFFFFFFFull);
  unsigned orig1 = (unsigned)(c2 & 0xFFFFFFFFull);

  const float* xb = x + (size_t)bb * CDIM * NDIM;
  const float* xxb = xxg + (size_t)bb * NDIM;

  // stage this row's x column (x[c][row], c=0..127) for rescan reuse
  __shared__ float xrow_s[4 * 128];
  xrow_s[wv * 128 + lane] = xb[(size_t)lane * NDIM + row];
  xrow_s[wv * 128 + 64 + lane] = xb[(size_t)(64 + lane) * NDIM + row];

  int my = 0;
  for (int s = 0; s < KSEL; ++s) {
    ull mx = c1;
#pragma unroll
    for (int off = 1; off < 64; off <<= 1) {
      ull o = __shfl_xor(mx, off);
      mx = o > mx ? o : mx;
    }
    if (lane == s) my = 4095 - (int)(unsigned)(mx & 0xFFFFFFFFull);
    if (s < KSEL - 1) {
      bool iswin = (c1 == mx);
      ull bal = __ballot(iswin && (c2 == 0ull));
      if (iswin) { c1 = c2; c2 = 0ull; }
      if (bal) {
        int g = (int)(__ffsll((long long)bal) - 1);
        unsigned e0 = __shfl(orig0, g), e1 = __shfl(orig1, g);
        int col = g * 64 + lane;
        const float* xc = xb + col;
        const float* xrs = xrow_s + wv * 128;
        float d = 0.f;
        for (int cc = 0; cc < 128; ++cc)
          d = __builtin_fmaf(xc[(size_t)cc * NDIM], xrs[cc], d);
        float sv = __builtin_fmaf(2.f, d, -xxb[col]);
        unsigned low = 4095u - (unsigned)col;
        ull key = makekey(sv, low);
        if (key >= mx || low == e0 || low == e1) key = 0ull;
        ull r1 = key;
#pragma unroll
        for (int off = 1; off < 64; off <<= 1) {
          ull o = __shfl_xor(r1, off);
          r1 = o > r1 ? o : r1;
        }
        ull key2 = (key == r1) ? 0ull : key;
        ull r2 = key2;
#pragma unroll
        for (int off = 1; off < 64; off <<= 1) {
          ull o = __shfl_xor(r2, off);
          r2 = o > r2 ? o : r2;
        }
        if (lane == g) { c1 = r1; c2 = r2; }
      }
    }
  }
  if (lane < KSEL)
    idxout[((size_t)bb * NDIM + row) * KSEL + lane] = my;
}

// ---------------------------------------------------------------------------
// Kernel C: Md[b][c][n] = mean_k x[b][c][idx[b][n][k]] - x[b][c][n]
// int4 x10 idx loads, float4 stores.
// ---------------------------------------------------------------------------
__global__ __launch_bounds__(256) void gather_kernel(const float* __restrict__ x,
                                                     const int* __restrict__ idxg,
                                                     float* __restrict__ Md) {
  const int N = NDIM;
  int bb = blockIdx.y, c = blockIdx.x;
  __shared__ float row_s[NDIM];
  const float* rowg = x + (size_t)(bb * CDIM + c) * N;
  int t = threadIdx.x;
#pragma unroll
  for (int p = 0; p < 4; ++p) {
    int i4 = t + 256 * p;
    *(float4*)&row_s[i4 * 4] = *(const float4*)&rowg[i4 * 4];
  }
  __syncthreads();
  float* outp = Md + (size_t)(bb * CDIM + c) * N;
  const int* ib = idxg + (size_t)bb * N * KSEL;
#pragma unroll
  for (int p = 0; p < 4; ++p) {
    int n = (t + 256 * p) * 4;
    const int4* ip4 = (const int4*)(ib + (size_t)n * KSEL);
    int4 w[10];
#pragma unroll
    for (int k = 0; k < 10; ++k) w[k] = ip4[k];
    const int* wi = (const int*)w;
    float4 r;
    float* rr = (float*)&r;
#pragma unroll
    for (int q = 0; q < 4; ++q) {
      float s = 0.f;
#pragma unroll
      for (int k = 0; k < KSEL; ++k) s += row_s[wi[q * KSEL + k]];
      rr[q] = s * 0.1f - row_s[n + q];
    }
    *(float4*)&outp[n] = r;
  }
}

// ---------------------------------------------------------------------------
// Kernel D: out via pre-transposed WT. T3 2-phase double-buffered staging
// (R12 version — VALU FMAs; MFMA variant measured slower at this GEMM size).
// ---------------------------------------------------------------------------
__global__ __launch_bounds__(256) void out_kernel(const float* __restrict__ Md,
                                                  const float* __restrict__ x,
                                                  const float* __restrict__ WT,
                                                  const float* __restrict__ bias,
                                                  float* __restrict__ out) {
  const int N = NDIM, O = 256;
  int bb = blockIdx.z;
  int o0 = blockIdx.y * 64;
  int n0 = blockIdx.x * 128;
  int t = threadIdx.x;
  int tx = t & 15, ty = t >> 4;
  int tx4 = tx * 4, ty4 = ty * 4;

  // 2 buffers x (wt[32][64]=2048 + src[32][128]=4096) = 12288 floats = 48 KB
  __shared__ float smem[12288];

  float acc[4][8];
#pragma unroll
  for (int i = 0; i < 4; ++i)
#pragma unroll
    for (int j = 0; j < 8; ++j) acc[i][j] = 0.f;

  auto stage = [&](float* buf, int ch) {
    const float* src = (ch < 4)
        ? Md + (size_t)(bb * CDIM + ch * 32) * N
        : x + (size_t)(bb * CDIM + (ch - 4) * 32) * N;
    float* wt_s = buf;
    float* src_s = buf + 2048;
#pragma unroll
    for (int p = 0; p < 2; ++p) {
      int i4 = t + 256 * p;
      async_cp16(&wt_s[i4 * 4], &WT[(size_t)(ch * 32 + (i4 >> 4)) * O + o0 + (i4 & 15) * 4]);
    }
#pragma unroll
    for (int p = 0; p < 4; ++p) {
      int i4 = t + 256 * p;
      async_cp16(&src_s[i4 * 4], &src[(size_t)(i4 >> 5) * N + n0 + (i4 & 31) * 4]);
    }
  };

  stage(smem, 0);  // prologue prefetch

  for (int ch = 0; ch < 8; ++ch) {
    __syncthreads();
    float* cur = smem + (ch & 1) * 6144;
    if (ch < 7) stage(smem + ((ch + 1) & 1) * 6144, ch + 1);

    float* wt_s = cur;
    float* src_s = cur + 2048;
#pragma unroll 4
    for (int cc = 0; cc < 32; ++cc) {
      float4 a = *(const float4*)&wt_s[cc * 64 + ty4];
      float4 b0 = *(const float4*)&src_s[cc * 128 + tx4];
      float4 b1 = *(const float4*)&src_s[cc * 128 + tx4 + 64];
      float av[4] = {a.x, a.y, a.z, a.w};
      float bv[8] = {b0.x, b0.y, b0.z, b0.w, b1.x, b1.y, b1.z, b1.w};
#pragma unroll
      for (int i = 0; i < 4; ++i)
#pragma unroll
        for (int j = 0; j < 8; ++j) acc[i][j] += av[i] * bv[j];
    }
  }

#pragma unroll
  for (int i = 0; i < 4; ++i) {
    int o = o0 + ty4 + i;
    float bv = bias[o];
    float* po = out + (size_t)(bb * O + o) * N + n0;
    *(float4*)&po[tx4] = make_float4(acc[i][0] + bv, acc[i][1] + bv,
                                     acc[i][2] + bv, acc[i][3] + bv);
    *(float4*)&po[tx4 + 64] = make_float4(acc[i][4] + bv, acc[i][5] + bv,
                                          acc[i][6] + bv, acc[i][7] + bv);
  }
}

// ---------------------------------------------------------------------------
extern "C" void kernel_launch(void* const* d_in, const int* in_sizes, int n_in,
                              void* d_out, int out_size, void* d_ws, size_t ws_size,
                              hipStream_t stream) {
  const float* x = (const float*)d_in[0];     // (4,128,4096) fp32
  const float* W = (const float*)d_in[1];     // (256,256,1,1) fp32
  const float* bias = (const float*)d_in[2];  // (256,) fp32
  float* out = (float*)d_out;                 // (4,256,4096) fp32

  // ws carve: xx 64K | idx 640K | Md 8M | pc 16M | WT 256K at top.
  // Job counter lives in `out` (fully overwritten later).
  float* xx = (float*)d_ws;
  int* idx = (int*)((char*)d_ws + 65536);
  float* Md = (float*)((char*)d_ws + 65536 + 655360);
  const size_t fixed = 9109504;
  ull* pc = (ull*)((char*)d_ws + fixed);      // 4 batches x 4096x128 u64 = 16 MB
  size_t wt_off = (ws_size - 262144) & ~(size_t)255;
  float* WT = (float*)((char*)d_ws + wt_off);
  unsigned* ctr = (unsigned*)out;

  xx_kernel<<<dim3(256), 256, 0, stream>>>(x, xx);
  wtrans_kernel<<<dim3(256), 256, 0, stream>>>(W, WT, ctr);
  score_kernel<<<dim3(768), 256, 0, stream>>>(x, xx, pc, ctr);
  merge_kernel<<<dim3(1024, 4), 256, 0, stream>>>(x, xx, pc, idx);
  gather_kernel<<<dim3(128, 4), 256, 0, stream>>>(x, idx, Md);
  out_kernel<<<dim3(32, 4, 4), 256, 0, stream>>>(Md, x, WT, bias, out);
}